// Round 2
// baseline (57.891 us; speedup 1.0000x reference)
//
#include <hip/hip_runtime.h>
#include <math.h>

#define NT 50
#define NC 20
#define NB 64

// anchors / stride, per scale: scale0 fs=52 (stride 8, masks 6,7,8),
// scale1 fs=26 (stride16, masks 3,4,5), scale2 fs=13 (stride32, masks 0,1,2)
__device__ __constant__ float c_aw[3][3] = {
    {14.5f, 19.5f, 46.625f},
    {1.875f, 3.875f, 3.6875f},
    {0.3125f, 0.5f, 1.03125f}};
__device__ __constant__ float c_ah[3][3] = {
    {11.25f, 24.75f, 40.75f},
    {3.8125f, 2.8125f, 7.4375f},
    {0.40625f, 0.9375f, 0.71875f}};

__global__ void zero_out_kernel(float* out) { out[0] = 0.0f; }

__global__ __launch_bounds__(256) void yolo_loss_kernel(
    const float* __restrict__ pred0, const float* __restrict__ pred1,
    const float* __restrict__ pred2, const float* __restrict__ boxes,
    const int* __restrict__ cls, float* __restrict__ out) {
  // block decode: 42 blocks per batch: 32 (scale0) + 8 (scale1) + 2 (scale2)
  int bid = blockIdx.x;
  int b = bid / 42;
  int r = bid % 42;
  int scale, chunk;
  if (r < 32) { scale = 0; chunk = r; }
  else if (r < 40) { scale = 1; chunk = r - 32; }
  else { scale = 2; chunk = r - 40; }

  const int fs = (scale == 0) ? 52 : ((scale == 1) ? 26 : 13);
  const int cells = fs * fs * 3;
  const float* pred = (scale == 0) ? pred0 : ((scale == 1) ? pred1 : pred2);
  const float invN = 1.0f / (float)(NB * cells);

  __shared__ float s_pred[6400];  // 256 cells x 25 ch = 25.6 KB
  __shared__ int s_cell[NT];
  __shared__ float s_tcx[NT], s_tcy[NT], s_tww[NT], s_thh[NT];
  __shared__ int s_bit[NT];
  __shared__ float s_red[4];

  const int tid = threadIdx.x;

  // ---- stage this block's pred region into LDS (coalesced) ----
  const float* src = pred + (size_t)b * fs * fs * 75 + (size_t)chunk * 6400;
  int count = cells * 25 - chunk * 6400;
  if (count > 6400) count = 6400;
  if (((((size_t)src) & 15) == 0) && ((count & 3) == 0)) {
    int n4 = count >> 2;
    const float4* src4 = (const float4*)src;
    for (int i = tid; i < n4; i += 256) {
      float4 v = src4[i];
      s_pred[i * 4 + 0] = v.x;
      s_pred[i * 4 + 1] = v.y;
      s_pred[i * 4 + 2] = v.z;
      s_pred[i * 4 + 3] = v.w;
    }
  } else {
    // scale2 odd-batch offsets are only 4B-aligned (~5% of work)
    for (int i = tid; i < count; i += 256) s_pred[i] = src[i];
  }

  // ---- per-target prep ----
  if (tid < NT) {
    const float* bx = boxes + ((size_t)b * NT + tid) * 4;
    float ffs = (float)fs;
    float tbx = bx[0] * ffs;
    float tby = bx[1] * ffs;
    float tw = bx[2] * ffs;
    float th = bx[3] * ffs;
    float bestr = -1.0f;
    int best = 0;
    for (int a = 0; a < 3; ++a) {
      float aw = c_aw[scale][a], ah = c_ah[scale][a];
      float inter = fminf(tw, aw) * fminf(th, ah);
      float uni = tw * th + aw * ah - inter;
      float rr = inter / (uni + 1e-6f);
      if (rr > bestr) { bestr = rr; best = a; }
    }
    int gx = (int)tbx;
    if (gx < 0) gx = 0;
    if (gx > fs - 1) gx = fs - 1;
    int gy = (int)tby;
    if (gy < 0) gy = 0;
    if (gy > fs - 1) gy = fs - 1;
    s_cell[tid] = (gy * fs + gx) * 3 + best;
    s_tcx[tid] = tbx - (float)gx;
    s_tcy[tid] = tby - (float)gy;
    s_tww[tid] = logf(tw / c_aw[scale][best] + 1e-6f);
    s_thh[tid] = logf(th / c_ah[scale][best] + 1e-6f);
    s_bit[tid] = 1 << cls[(size_t)b * NT + tid];
  }
  __syncthreads();

  int cell = chunk * 256 + tid;
  float contrib = 0.0f;
  if (cell < cells) {
    const float* p = s_pred + tid * 25;  // stride-25 LDS: <=2-way alias, free
    int a = cell % 3;
    int gxy = cell / 3;
    int gx = gxy % fs;
    int gy = gxy / fs;

    // scan targets: last match wins (in-order scatter), class bits union
    int win = -1;
    unsigned mask = 0;
    for (int t = 0; t < NT; ++t) {
      if (s_cell[t] == cell) {
        win = t;
        mask |= (unsigned)s_bit[t];
      }
    }

    float pconf = 1.0f / (1.0f + expf(-p[4]));
    if (win >= 0) {
      float aw = c_aw[scale][a], ah = c_ah[scale][a];
      float scx = 1.0f / (1.0f + expf(-p[0])) + (float)gx;
      float scy = 1.0f / (1.0f + expf(-p[1])) + (float)gy;
      float pw = expf(p[2]) * aw;
      float ph = expf(p[3]) * ah;
      float dcx = scx - s_tcx[win];
      float dcy = scy - s_tcy[win];
      float dw = pw - s_tww[win];
      float dh = ph - s_thh[win];
      float coord = dcx * dcx + dcy * dcy + dw * dw + dh * dh;
      float bobj = -logf(fmaxf(pconf, 1e-12f));
      float csum = 0.0f;
      for (int c = 0; c < NC; ++c) {
        float pc = 1.0f / (1.0f + expf(-p[5 + c]));
        if ((mask >> c) & 1u)
          csum += -logf(fmaxf(pc, 1e-12f));
        else
          csum += -logf(fmaxf(1.0f - pc, 1e-12f));
      }
      contrib = (coord * 5.0f + bobj) * invN + csum * (invN * (1.0f / (float)NC));
    } else {
      float bno = -logf(fmaxf(1.0f - pconf, 1e-12f));
      contrib = 0.5f * bno * invN;
    }
    contrib *= (1.0f / 3.0f);
  }

  // ---- reduction: wave shuffle, then 4 partials via LDS ----
  for (int off = 32; off > 0; off >>= 1) contrib += __shfl_down(contrib, off);
  if ((tid & 63) == 0) s_red[tid >> 6] = contrib;
  __syncthreads();
  if (tid == 0) atomicAdd(out, s_red[0] + s_red[1] + s_red[2] + s_red[3]);
}

extern "C" void kernel_launch(void* const* d_in, const int* in_sizes, int n_in,
                              void* d_out, int out_size, void* d_ws, size_t ws_size,
                              hipStream_t stream) {
  const float* pred0 = (const float*)d_in[0];
  const float* pred1 = (const float*)d_in[1];
  const float* pred2 = (const float*)d_in[2];
  const float* boxes = (const float*)d_in[3];
  const int* cls = (const int*)d_in[4];
  float* out = (float*)d_out;

  zero_out_kernel<<<1, 1, 0, stream>>>(out);
  yolo_loss_kernel<<<NB * 42, 256, 0, stream>>>(pred0, pred1, pred2, boxes, cls, out);
}

// Round 3
// 32.310 us; speedup vs baseline: 1.7917x; 1.7917x over previous
//
#include <hip/hip_runtime.h>
#include <math.h>

#define NT 50
#define NC 20
#define NB 64
#define NBLK (NB * 42)

// anchors / stride, per scale: scale0 fs=52 (stride 8, masks 6,7,8),
// scale1 fs=26 (stride16, masks 3,4,5), scale2 fs=13 (stride32, masks 0,1,2)
__device__ __constant__ float c_aw[3][3] = {
    {14.5f, 19.5f, 46.625f},
    {1.875f, 3.875f, 3.6875f},
    {0.3125f, 0.5f, 1.03125f}};
__device__ __constant__ float c_ah[3][3] = {
    {11.25f, 24.75f, 40.75f},
    {3.8125f, 2.8125f, 7.4375f},
    {0.40625f, 0.9375f, 0.71875f}};

__global__ __launch_bounds__(256) void yolo_loss_kernel(
    const float* __restrict__ pred0, const float* __restrict__ pred1,
    const float* __restrict__ pred2, const float* __restrict__ boxes,
    const int* __restrict__ cls, float* __restrict__ ws) {
  // block decode: 42 blocks per batch: 32 (scale0) + 8 (scale1) + 2 (scale2)
  int bid = blockIdx.x;
  int b = bid / 42;
  int r = bid % 42;
  int scale, chunk;
  if (r < 32) { scale = 0; chunk = r; }
  else if (r < 40) { scale = 1; chunk = r - 32; }
  else { scale = 2; chunk = r - 40; }

  const int fs = (scale == 0) ? 52 : ((scale == 1) ? 26 : 13);
  const int cells = fs * fs * 3;
  const float* pred = (scale == 0) ? pred0 : ((scale == 1) ? pred1 : pred2);
  const float invN = 1.0f / (float)(NB * cells);

  __shared__ int s_cell[NT];
  __shared__ float s_tcx[NT], s_tcy[NT], s_tww[NT], s_thh[NT];
  __shared__ int s_bit[NT];
  __shared__ float s_red[4];

  const int tid = threadIdx.x;

  if (tid < NT) {
    const float* bx = boxes + ((size_t)b * NT + tid) * 4;
    float ffs = (float)fs;
    float tbx = bx[0] * ffs;
    float tby = bx[1] * ffs;
    float tw = bx[2] * ffs;
    float th = bx[3] * ffs;
    // best anchor: argmax of inter/(union+1e-6), first index wins ties
    float bestr = -1.0f;
    int best = 0;
    for (int a = 0; a < 3; ++a) {
      float aw = c_aw[scale][a], ah = c_ah[scale][a];
      float inter = fminf(tw, aw) * fminf(th, ah);
      float uni = tw * th + aw * ah - inter;
      float rr = inter / (uni + 1e-6f);
      if (rr > bestr) { bestr = rr; best = a; }
    }
    int gx = (int)tbx;
    if (gx < 0) gx = 0;
    if (gx > fs - 1) gx = fs - 1;
    int gy = (int)tby;
    if (gy < 0) gy = 0;
    if (gy > fs - 1) gy = fs - 1;
    s_cell[tid] = (gy * fs + gx) * 3 + best;
    s_tcx[tid] = tbx - (float)gx;
    s_tcy[tid] = tby - (float)gy;
    s_tww[tid] = logf(tw / c_aw[scale][best] + 1e-6f);
    s_thh[tid] = logf(th / c_ah[scale][best] + 1e-6f);
    s_bit[tid] = 1 << cls[(size_t)b * NT + tid];
  }
  __syncthreads();

  int cell = chunk * 256 + tid;
  float contrib = 0.0f;
  if (cell < cells) {
    int a = cell % 3;
    int gxy = cell / 3;
    int gx = gxy % fs;
    int gy = gxy / fs;
    const float* p = pred + (((size_t)b * fs + gy) * fs + gx) * 75 + a * 25;

    // scan targets: last match wins (in-order scatter), class bits union
    int win = -1;
    unsigned mask = 0;
    for (int t = 0; t < NT; ++t) {
      if (s_cell[t] == cell) {
        win = t;
        mask |= (unsigned)s_bit[t];
      }
    }

    float pconf = 1.0f / (1.0f + expf(-p[4]));
    if (win >= 0) {
      float aw = c_aw[scale][a], ah = c_ah[scale][a];
      float scx = 1.0f / (1.0f + expf(-p[0])) + (float)gx;
      float scy = 1.0f / (1.0f + expf(-p[1])) + (float)gy;
      float pw = expf(p[2]) * aw;
      float ph = expf(p[3]) * ah;
      float dcx = scx - s_tcx[win];
      float dcy = scy - s_tcy[win];
      float dw = pw - s_tww[win];
      float dh = ph - s_thh[win];
      float coord = dcx * dcx + dcy * dcy + dw * dw + dh * dh;
      float bobj = -logf(fmaxf(pconf, 1e-12f));
      float csum = 0.0f;
      for (int c = 0; c < NC; ++c) {
        float pc = 1.0f / (1.0f + expf(-p[5 + c]));
        if ((mask >> c) & 1u)
          csum += -logf(fmaxf(pc, 1e-12f));
        else
          csum += -logf(fmaxf(1.0f - pc, 1e-12f));
      }
      contrib = (coord * 5.0f + bobj) * invN + csum * (invN * (1.0f / (float)NC));
    } else {
      float bno = -logf(fmaxf(1.0f - pconf, 1e-12f));
      contrib = 0.5f * bno * invN;
    }
    contrib *= (1.0f / 3.0f);
  }

  // ---- reduction: wave shuffle, then 4 partials via LDS ----
  for (int off = 32; off > 0; off >>= 1) contrib += __shfl_down(contrib, off);
  if ((tid & 63) == 0) s_red[tid >> 6] = contrib;
  __syncthreads();
  if (tid == 0) ws[bid] = s_red[0] + s_red[1] + s_red[2] + s_red[3];
}

__global__ __launch_bounds__(256) void reduce_kernel(
    const float* __restrict__ ws, float* __restrict__ out) {
  __shared__ float s_red[4];
  int tid = threadIdx.x;
  float v = 0.0f;
  for (int i = tid; i < NBLK; i += 256) v += ws[i];
  for (int off = 32; off > 0; off >>= 1) v += __shfl_down(v, off);
  if ((tid & 63) == 0) s_red[tid >> 6] = v;
  __syncthreads();
  if (tid == 0) out[0] = s_red[0] + s_red[1] + s_red[2] + s_red[3];
}

extern "C" void kernel_launch(void* const* d_in, const int* in_sizes, int n_in,
                              void* d_out, int out_size, void* d_ws, size_t ws_size,
                              hipStream_t stream) {
  const float* pred0 = (const float*)d_in[0];
  const float* pred1 = (const float*)d_in[1];
  const float* pred2 = (const float*)d_in[2];
  const float* boxes = (const float*)d_in[3];
  const int* cls = (const int*)d_in[4];
  float* out = (float*)d_out;
  float* ws = (float*)d_ws;

  yolo_loss_kernel<<<NBLK, 256, 0, stream>>>(pred0, pred1, pred2, boxes, cls, ws);
  reduce_kernel<<<1, 256, 0, stream>>>(ws, out);
}